// Round 1
// baseline (4622.281 us; speedup 1.0000x reference)
//
#include <hip/hip_runtime.h>
#include <cstdint>
#include <cstddef>

#define BB 4
#define CC 2048
#define HH 48
#define WW 48
#define NN 2304       // HH*WW
#define CAMS 384

// ---------------- workspace layout (floats) ----------------
// q:    BB*CC*NN = 18,874,368
// k:    BB*CC*NN
// e:    BB*NN*NN = 21,233,664   (energy, softmaxed in place -> atten)
// qn2:  BB*NN
// kn2:  BB*NN
// mask: BB*NN
// acc:  double sum (2 float slots) + uint count (1 slot)
// total ~236.1 MB — assumed <= ws_size.

// ---------------- mask from cam (bilinear, align_corners) ----------------
__global__ void mask_kernel(const float* __restrict__ cam, float* __restrict__ mask) {
    int idx = blockIdx.x * blockDim.x + threadIdx.x;
    if (idx >= BB * NN) return;
    int b = idx / NN, p = idx % NN;
    int y = p / WW, xx = p % WW;
    float ys = (float)(y  * (CAMS - 1)) / (float)(HH - 1);
    float xs = (float)(xx * (CAMS - 1)) / (float)(WW - 1);
    int y0 = (int)ys, x0 = (int)xs;                 // >=0, floor==trunc
    int y1 = min(y0 + 1, CAMS - 1), x1 = min(x0 + 1, CAMS - 1);
    float wy = ys - (float)y0, wx = xs - (float)x0;
    const float* cb = cam + (size_t)b * CAMS * CAMS;
    float c00 = cb[y0 * CAMS + x0]; if (c00 == 255.f) c00 = 0.f;
    float c01 = cb[y0 * CAMS + x1]; if (c01 == 255.f) c01 = 0.f;
    float c10 = cb[y1 * CAMS + x0]; if (c10 == 255.f) c10 = 0.f;
    float c11 = cb[y1 * CAMS + x1]; if (c11 == 255.f) c11 = 0.f;
    float top = (1.f - wx) * c00 + wx * c01;
    float bot = (1.f - wx) * c10 + wx * c11;
    float v = (1.f - wy) * top + wy * bot;
    mask[idx] = (v > 0.f) ? 1.f : 0.f;
}

// ---------------- init: zero norm accumulators + loss accumulators ----------------
__global__ void init_kernel(float* __restrict__ qn2, float* __restrict__ kn2,
                            float* __restrict__ accf) {
    int t = blockIdx.x * blockDim.x + threadIdx.x;
    if (t < BB * NN) { qn2[t] = 0.f; kn2[t] = 0.f; }
    if (t == 0) { ((double*)accf)[0] = 0.0; ((unsigned int*)accf)[2] = 0u; }
}

// ---------------- projection GEMM: out[b,o,n] = sum_c W[o,c]*x[b,c,n] + bias[o] ----------------
__global__ __launch_bounds__(256) void gemm_proj(const float* __restrict__ Wm,
                                                 const float* __restrict__ bias,
                                                 const float* __restrict__ x,
                                                 float* __restrict__ out) {
    __shared__ float As[16][68];   // [k][m], pad 68 keeps rows 16B-aligned
    __shared__ float Bs[16][68];   // [k][n]
    const int b = blockIdx.z;
    const float* Bmat = x + (size_t)b * CC * NN;
    float* Cmat = out + (size_t)b * CC * NN;
    const int t = threadIdx.x;
    const int tx = t & 15, ty = t >> 4;
    const int m0 = blockIdx.y * 64, n0 = blockIdx.x * 64;
    float acc[4][4] = {};
    for (int k0 = 0; k0 < CC; k0 += 16) {
#pragma unroll
        for (int i = 0; i < 4; i++) {
            int lin = t + i * 256;
            As[lin & 15][lin >> 4] = Wm[(size_t)(m0 + (lin >> 4)) * CC + k0 + (lin & 15)];
        }
#pragma unroll
        for (int i = 0; i < 4; i++) {
            int lin = t + i * 256;
            Bs[lin >> 6][lin & 63] = Bmat[(size_t)(k0 + (lin >> 6)) * NN + n0 + (lin & 63)];
        }
        __syncthreads();
#pragma unroll
        for (int kk = 0; kk < 16; kk++) {
            float a[4], bb[4];
#pragma unroll
            for (int i = 0; i < 4; i++) a[i] = As[kk][ty * 4 + i];
#pragma unroll
            for (int j = 0; j < 4; j++) bb[j] = Bs[kk][tx * 4 + j];
#pragma unroll
            for (int i = 0; i < 4; i++)
#pragma unroll
                for (int j = 0; j < 4; j++) acc[i][j] += a[i] * bb[j];
        }
        __syncthreads();
    }
#pragma unroll
    for (int i = 0; i < 4; i++) {
        int m = m0 + ty * 4 + i;
        float bv = bias[m];
#pragma unroll
        for (int j = 0; j < 4; j++)
            Cmat[(size_t)m * NN + n0 + tx * 4 + j] = acc[i][j] + bv;
    }
}

// ---------------- norms: qn2[b,n] = sum_o q[b,o,n]^2 (partials via atomics) ----------------
__global__ __launch_bounds__(256) void norm_kernel(const float* __restrict__ q,
                                                   const float* __restrict__ k,
                                                   float* __restrict__ qn2,
                                                   float* __restrict__ kn2) {
    const int z = blockIdx.z;            // b*2 + which
    const int b = z >> 1;
    const float* src = (z & 1) ? k : q;
    float* dst = (z & 1) ? kn2 : qn2;
    const int n = blockIdx.x * 256 + threadIdx.x;   // 9 * 256 = 2304
    const int o0 = blockIdx.y * 128;                // 16 chunks
    const float* p = src + (size_t)b * CC * NN + (size_t)o0 * NN + n;
    float s = 0.f;
#pragma unroll 4
    for (int o = 0; o < 128; o++) { float v = p[(size_t)o * NN]; s += v * v; }
    atomicAdd(&dst[b * NN + n], s);
}

// ---------------- energy GEMM: e[b,n,m] = sum_o q[b,o,n]*k[b,o,m] ----------------
__global__ __launch_bounds__(256) void gemm_energy(const float* __restrict__ q,
                                                   const float* __restrict__ k,
                                                   float* __restrict__ e) {
    __shared__ float As[16][68];   // [o][n]
    __shared__ float Bs[16][68];   // [o][m]
    const int b = blockIdx.z;
    const float* Am = q + (size_t)b * CC * NN;
    const float* Bm = k + (size_t)b * CC * NN;
    float* Em = e + (size_t)b * NN * NN;
    const int t = threadIdx.x;
    const int tx = t & 15, ty = t >> 4;
    const int n0 = blockIdx.y * 64, m0 = blockIdx.x * 64;
    float acc[4][4] = {};
    for (int k0 = 0; k0 < CC; k0 += 16) {
#pragma unroll
        for (int i = 0; i < 4; i++) {
            int lin = t + i * 256;
            As[lin >> 6][lin & 63] = Am[(size_t)(k0 + (lin >> 6)) * NN + n0 + (lin & 63)];
            Bs[lin >> 6][lin & 63] = Bm[(size_t)(k0 + (lin >> 6)) * NN + m0 + (lin & 63)];
        }
        __syncthreads();
#pragma unroll
        for (int kk = 0; kk < 16; kk++) {
            float a[4], bb[4];
#pragma unroll
            for (int i = 0; i < 4; i++) a[i] = As[kk][ty * 4 + i];
#pragma unroll
            for (int j = 0; j < 4; j++) bb[j] = Bs[kk][tx * 4 + j];
#pragma unroll
            for (int i = 0; i < 4; i++)
#pragma unroll
                for (int j = 0; j < 4; j++) acc[i][j] += a[i] * bb[j];
        }
        __syncthreads();
    }
#pragma unroll
    for (int i = 0; i < 4; i++)
#pragma unroll
        for (int j = 0; j < 4; j++)
            Em[(size_t)(n0 + ty * 4 + i) * NN + m0 + tx * 4 + j] = acc[i][j];
}

// ---------------- softmax over m with 1/(qn*kn) scaling, then mask row ----------------
__global__ __launch_bounds__(256) void softmax_kernel(float* __restrict__ e,
                                                      const float* __restrict__ qn2,
                                                      const float* __restrict__ kn2,
                                                      const float* __restrict__ mask) {
    const int n = blockIdx.x, b = blockIdx.y;
    float* row = e + ((size_t)b * NN + n) * NN;
    const float qinv = rsqrtf(qn2[b * NN + n]);
    const float mval = mask[b * NN + n];
    const int t = threadIdx.x;
    float v[9];
    float vmax = -3.4e38f;
#pragma unroll
    for (int i = 0; i < 9; i++) {
        int idx = t + i * 256;               // 9*256 = 2304
        float s = row[idx] * qinv * rsqrtf(kn2[b * NN + idx]);
        v[i] = s;
        vmax = fmaxf(vmax, s);
    }
    __shared__ float red[8];
#pragma unroll
    for (int o = 32; o; o >>= 1) vmax = fmaxf(vmax, __shfl_down(vmax, o, 64));
    int lane = t & 63, wid = t >> 6;
    if (!lane) red[wid] = vmax;
    __syncthreads();
    vmax = fmaxf(fmaxf(red[0], red[1]), fmaxf(red[2], red[3]));
    float s = 0.f;
#pragma unroll
    for (int i = 0; i < 9; i++) { v[i] = __expf(v[i] - vmax); s += v[i]; }
#pragma unroll
    for (int o = 32; o; o >>= 1) s += __shfl_down(s, o, 64);
    if (!lane) red[4 + wid] = s;
    __syncthreads();
    s = red[4] + red[5] + red[6] + red[7];
    float scale = mval / s;
#pragma unroll
    for (int i = 0; i < 9; i++) row[t + i * 256] = v[i] * scale;
}

// ---------------- new_x GEMM + fused loss: nx[b,c,n]=sum_m x[b,c,m]*att[b,n,m] ----------------
__global__ __launch_bounds__(256) void gemm_out_loss(const float* __restrict__ x,
                                                     const float* __restrict__ att,
                                                     const float* __restrict__ gamma,
                                                     float* __restrict__ accf) {
    __shared__ float As[16][68];   // [m][c]
    __shared__ float Bs[16][68];   // [m][n]
    const int b = blockIdx.z;
    const float* Xm = x + (size_t)b * CC * NN;
    const float* Tm = att + (size_t)b * NN * NN;
    const int t = threadIdx.x;
    const int tx = t & 15, ty = t >> 4;
    const int c0 = blockIdx.y * 64, n0 = blockIdx.x * 64;
    float acc[4][4] = {};
    for (int m0 = 0; m0 < NN; m0 += 16) {
#pragma unroll
        for (int i = 0; i < 4; i++) {
            int lin = t + i * 256;
            As[lin & 15][lin >> 4] = Xm[(size_t)(c0 + (lin >> 4)) * NN + m0 + (lin & 15)];
            Bs[lin & 15][lin >> 4] = Tm[(size_t)(n0 + (lin >> 4)) * NN + m0 + (lin & 15)];
        }
        __syncthreads();
#pragma unroll
        for (int kk = 0; kk < 16; kk++) {
            float a[4], bb[4];
#pragma unroll
            for (int i = 0; i < 4; i++) a[i] = As[kk][ty * 4 + i];
#pragma unroll
            for (int j = 0; j < 4; j++) bb[j] = Bs[kk][tx * 4 + j];
#pragma unroll
            for (int i = 0; i < 4; i++)
#pragma unroll
                for (int j = 0; j < 4; j++) acc[i][j] += a[i] * bb[j];
        }
        __syncthreads();
    }
    const float g = gamma[0];
    float lsum = 0.f;
    unsigned int lcnt = 0;
#pragma unroll
    for (int i = 0; i < 4; i++) {
        int c = c0 + ty * 4 + i;
#pragma unroll
        for (int j = 0; j < 4; j++) {
            int n = n0 + tx * 4 + j;
            float xv = Xm[(size_t)c * NN + n];
            float d = xv - g * acc[i][j];
            float r = d * d;
            lsum += r;
            lcnt += (r != 0.f) ? 1u : 0u;
        }
    }
#pragma unroll
    for (int o = 32; o; o >>= 1) {
        lsum += __shfl_down(lsum, o, 64);
        lcnt += __shfl_down(lcnt, o, 64);
    }
    __shared__ float rs[4];
    __shared__ unsigned int rc[4];
    int lane = t & 63, wid = t >> 6;
    if (!lane) { rs[wid] = lsum; rc[wid] = lcnt; }
    __syncthreads();
    if (t == 0) {
        double tot = (double)rs[0] + rs[1] + rs[2] + rs[3];
        unsigned int ct = rc[0] + rc[1] + rc[2] + rc[3];
        atomicAdd((double*)accf, tot);
        atomicAdd(((unsigned int*)accf) + 2, ct);
    }
}

__global__ void finalize_kernel(const float* __restrict__ accf, float* __restrict__ out) {
    double s = ((const double*)accf)[0];
    unsigned int c = ((const unsigned int*)accf)[2];
    out[0] = (float)(s / (double)c);
}

extern "C" void kernel_launch(void* const* d_in, const int* in_sizes, int n_in,
                              void* d_out, int out_size, void* d_ws, size_t ws_size,
                              hipStream_t stream) {
    const float* x     = (const float*)d_in[0];
    const float* cam   = (const float*)d_in[1];
    const float* Wq    = (const float*)d_in[2];
    const float* bq    = (const float*)d_in[3];
    const float* Wk    = (const float*)d_in[4];
    const float* bk    = (const float*)d_in[5];
    const float* gamma = (const float*)d_in[6];

    float* ws = (float*)d_ws;
    const size_t OFF_Q    = 0;
    const size_t OFF_K    = OFF_Q + (size_t)BB * CC * NN;
    const size_t OFF_E    = OFF_K + (size_t)BB * CC * NN;
    const size_t OFF_QN2  = OFF_E + (size_t)BB * NN * NN;
    const size_t OFF_KN2  = OFF_QN2 + (size_t)BB * NN;
    const size_t OFF_MASK = OFF_KN2 + (size_t)BB * NN;
    const size_t OFF_ACC  = OFF_MASK + (size_t)BB * NN;   // byte offset divisible by 8

    float* q    = ws + OFF_Q;
    float* k    = ws + OFF_K;
    float* e    = ws + OFF_E;
    float* qn2  = ws + OFF_QN2;
    float* kn2  = ws + OFF_KN2;
    float* mask = ws + OFF_MASK;
    float* acc  = ws + OFF_ACC;

    hipLaunchKernelGGL(init_kernel, dim3((BB * NN + 255) / 256), dim3(256), 0, stream,
                       qn2, kn2, acc);
    hipLaunchKernelGGL(mask_kernel, dim3((BB * NN + 255) / 256), dim3(256), 0, stream,
                       cam, mask);
    hipLaunchKernelGGL(gemm_proj, dim3(36, 32, 4), dim3(256), 0, stream, Wq, bq, x, q);
    hipLaunchKernelGGL(gemm_proj, dim3(36, 32, 4), dim3(256), 0, stream, Wk, bk, x, k);
    hipLaunchKernelGGL(norm_kernel, dim3(9, 16, 8), dim3(256), 0, stream, q, k, qn2, kn2);
    hipLaunchKernelGGL(gemm_energy, dim3(36, 36, 4), dim3(256), 0, stream, q, k, e);
    hipLaunchKernelGGL(softmax_kernel, dim3(NN, BB), dim3(256), 0, stream, e, qn2, kn2, mask);
    hipLaunchKernelGGL(gemm_out_loss, dim3(36, 32, 4), dim3(256), 0, stream, x, e, gamma, acc);
    hipLaunchKernelGGL(finalize_kernel, dim3(1), dim3(1), 0, stream, acc, (float*)d_out);
}

// Round 2
// 634.345 us; speedup vs baseline: 7.2867x; 7.2867x over previous
//
#include <hip/hip_runtime.h>
#include <cstdint>
#include <cstddef>

#define BB 4
#define CC 2048
#define HH 48
#define WW 48
#define NN 2304       // HH*WW
#define CAMS 384

typedef unsigned short ushort_t;
typedef short bf16x8 __attribute__((ext_vector_type(8)));
typedef float f32x4 __attribute__((ext_vector_type(4)));

// ---- bf16 helpers (manual RNE; precision irrelevant at 2e-2 threshold) ----
__device__ __forceinline__ ushort_t f2bf(float f) {
    uint32_t u = __builtin_bit_cast(uint32_t, f);
    u += 0x7FFFu + ((u >> 16) & 1u);
    return (ushort_t)(u >> 16);
}
__device__ __forceinline__ float bf2f(ushort_t u) {
    return __builtin_bit_cast(float, (uint32_t)u << 16);
}

// ---- LDS chunk swizzle: rows stride 64B; spread the four 16B chunks so a
// wave's 64 b128 lane-reads hit all 16B-aligned bank groups evenly ----
__device__ __forceinline__ int swz(int r) { return (r ^ (r >> 2)) & 3; }

__device__ __forceinline__ void gld16(const void* g, void* l) {
    __builtin_amdgcn_global_load_lds(
        (const __attribute__((address_space(1))) uint32_t*)g,
        (__attribute__((address_space(3))) uint32_t*)l, 16, 0, 0);
}

// ---- shared MFMA mainloop: D[m0..m0+128][n0..n0+128] += A[m][k]*B[n][k]
// A: [M][K] bf16 k-fast, B: [N][K] bf16 k-fast, K % 32 == 0.
// Block = 256 thr (4 waves, 2x2 wave grid, 64x64 per wave, 4x4 frags). ----
__device__ __forceinline__ void mfma_mainloop(
    const ushort_t* __restrict__ A, const ushort_t* __restrict__ B, int K,
    int m0, int n0, ushort_t* sA, ushort_t* sB, f32x4 acc[4][4])
{
    const int t = threadIdx.x;
    const int lane = t & 63;
    const int w = t >> 6;
    const int wm = (w >> 1) * 64;
    const int wn = (w & 1) * 64;
    const int col = lane & 15;
    const int quad = lane >> 4;
    const int lrow = lane >> 2;     // 0..15 within a 16-row staging group
    const int lchk = lane & 3;      // physical 16B chunk within 64B row

    for (int k0 = 0; k0 < K; k0 += 32) {
        __syncthreads();
        #pragma unroll
        for (int iss = 0; iss < 2; iss++) {
            const int rbase = w * 32 + iss * 16;      // wave-uniform
            const int ra = rbase + lrow;              // tile-local row
            const int ca = (lchk ^ swz(ra)) * 8;      // logical k-chunk (elems)
            gld16(A + (size_t)(m0 + ra) * K + k0 + ca, sA + rbase * 32);
            gld16(B + (size_t)(n0 + ra) * K + k0 + ca, sB + rbase * 32);
        }
        __syncthreads();
        bf16x8 af[4], bfr[4];
        #pragma unroll
        for (int i = 0; i < 4; i++) {
            const int m = wm + i * 16 + col;
            af[i] = *(const bf16x8*)(sA + m * 32 + (quad ^ swz(m)) * 8);
        }
        #pragma unroll
        for (int j = 0; j < 4; j++) {
            const int n = wn + j * 16 + col;
            bfr[j] = *(const bf16x8*)(sB + n * 32 + (quad ^ swz(n)) * 8);
        }
        #pragma unroll
        for (int i = 0; i < 4; i++)
            #pragma unroll
            for (int j = 0; j < 4; j++)
                acc[i][j] = __builtin_amdgcn_mfma_f32_16x16x32_bf16(
                    af[i], bfr[j], acc[i][j], 0, 0, 0);
    }
}

// ---------------- mask from cam (bilinear, align_corners) ----------------
__global__ void mask_kernel(const float* __restrict__ cam, float* __restrict__ mask) {
    int idx = blockIdx.x * blockDim.x + threadIdx.x;
    if (idx >= BB * NN) return;
    int b = idx / NN, p = idx % NN;
    int y = p / WW, xx = p % WW;
    float ys = (float)(y  * (CAMS - 1)) / (float)(HH - 1);
    float xs = (float)(xx * (CAMS - 1)) / (float)(WW - 1);
    int y0 = (int)ys, x0 = (int)xs;
    int y1 = min(y0 + 1, CAMS - 1), x1 = min(x0 + 1, CAMS - 1);
    float wy = ys - (float)y0, wx = xs - (float)x0;
    const float* cb = cam + (size_t)b * CAMS * CAMS;
    float c00 = cb[y0 * CAMS + x0]; if (c00 == 255.f) c00 = 0.f;
    float c01 = cb[y0 * CAMS + x1]; if (c01 == 255.f) c01 = 0.f;
    float c10 = cb[y1 * CAMS + x0]; if (c10 == 255.f) c10 = 0.f;
    float c11 = cb[y1 * CAMS + x1]; if (c11 == 255.f) c11 = 0.f;
    float top = (1.f - wx) * c00 + wx * c01;
    float bot = (1.f - wx) * c10 + wx * c11;
    float v = (1.f - wy) * top + wy * bot;
    mask[idx] = (v > 0.f) ? 1.f : 0.f;
}

__global__ void init_kernel(float* __restrict__ accf) {
    if (threadIdx.x == 0) { ((double*)accf)[0] = 0.0; ((unsigned int*)accf)[2] = 0u; }
}

// ---------------- W fp32 -> bf16 (layout unchanged, c fast) ----------------
__global__ void conv_w(const float* __restrict__ Wq, const float* __restrict__ Wk,
                       ushort_t* __restrict__ Wqb, ushort_t* __restrict__ Wkb) {
    const int per = CC * CC / 4;
    int idx = blockIdx.x * 256 + threadIdx.x;
    if (idx >= 2 * per) return;
    const float4* src; ushort_t* dst; int i;
    if (idx < per) { src = (const float4*)Wq; dst = Wqb; i = idx; }
    else           { src = (const float4*)Wk; dst = Wkb; i = idx - per; }
    float4 v = src[i];
    ushort_t* o = dst + (size_t)i * 4;
    o[0] = f2bf(v.x); o[1] = f2bf(v.y); o[2] = f2bf(v.z); o[3] = f2bf(v.w);
}

// ---------------- x fp32 [b][c][n] -> xbf bf16 same + xT bf16 [b][n][c] ----
__global__ void conv_x(const float* __restrict__ x, ushort_t* __restrict__ xbf,
                       ushort_t* __restrict__ xT) {
    __shared__ float tile[32][33];
    const int b = blockIdx.z;
    const int c0 = blockIdx.y * 32, n0 = blockIdx.x * 32;
    const int tx = threadIdx.x, ty = threadIdx.y;   // 32 x 8
    #pragma unroll
    for (int r = 0; r < 32; r += 8) {
        size_t gi = ((size_t)b * CC + c0 + ty + r) * NN + n0 + tx;
        float v = x[gi];
        xbf[gi] = f2bf(v);
        tile[ty + r][tx] = v;
    }
    __syncthreads();
    #pragma unroll
    for (int r = 0; r < 32; r += 8) {
        xT[((size_t)b * NN + n0 + ty + r) * CC + c0 + tx] = f2bf(tile[tx][ty + r]);
    }
}

// ---------------- proj: qT[b][n][o] = sum_c xT[n][c]*W[o][c] + bias[o] ----
__global__ __launch_bounds__(256) void gemm_proj(
    const ushort_t* __restrict__ xT, const ushort_t* __restrict__ Wb,
    const float* __restrict__ bias, ushort_t* __restrict__ outT)
{
    __shared__ __align__(16) ushort_t sA[128 * 32];
    __shared__ __align__(16) ushort_t sB[128 * 32];
    const int b = blockIdx.z;
    const int m0 = blockIdx.y * 128;   // n
    const int n0 = blockIdx.x * 128;   // o
    f32x4 acc[4][4];
    const f32x4 zz = {0.f, 0.f, 0.f, 0.f};
    #pragma unroll
    for (int i = 0; i < 4; i++)
        #pragma unroll
        for (int j = 0; j < 4; j++) acc[i][j] = zz;
    mfma_mainloop(xT + (size_t)b * NN * CC, Wb, CC, m0, n0, sA, sB, acc);
    const int t = threadIdx.x, lane = t & 63, w = t >> 6;
    const int wm = (w >> 1) * 64, wn = (w & 1) * 64;
    const int col = lane & 15, quad = lane >> 4;
    ushort_t* O = outT + (size_t)b * NN * CC;
    #pragma unroll
    for (int j = 0; j < 4; j++) {
        const int gn = n0 + wn + j * 16 + col;     // o
        const float bv = bias[gn];
        #pragma unroll
        for (int i = 0; i < 4; i++) {
            const int gm = m0 + wm + i * 16 + quad * 4;   // n
            #pragma unroll
            for (int r = 0; r < 4; r++)
                O[(size_t)(gm + r) * CC + gn] = f2bf(acc[i][j][r] + bv);
        }
    }
}

// ---------------- energy: S[b][n][m] = sum_o qT[n][o]*kT[m][o] (bf16) ----
__global__ __launch_bounds__(256) void gemm_energy(
    const ushort_t* __restrict__ qT, const ushort_t* __restrict__ kT,
    ushort_t* __restrict__ S)
{
    __shared__ __align__(16) ushort_t sA[128 * 32];
    __shared__ __align__(16) ushort_t sB[128 * 32];
    const int b = blockIdx.z;
    const int m0 = blockIdx.y * 128;   // n
    const int n0 = blockIdx.x * 128;   // m
    f32x4 acc[4][4];
    const f32x4 zz = {0.f, 0.f, 0.f, 0.f};
    #pragma unroll
    for (int i = 0; i < 4; i++)
        #pragma unroll
        for (int j = 0; j < 4; j++) acc[i][j] = zz;
    mfma_mainloop(qT + (size_t)b * NN * CC, kT + (size_t)b * NN * CC, CC,
                  m0, n0, sA, sB, acc);
    const int t = threadIdx.x, lane = t & 63, w = t >> 6;
    const int wm = (w >> 1) * 64, wn = (w & 1) * 64;
    const int col = lane & 15, quad = lane >> 4;
    ushort_t* O = S + (size_t)b * NN * NN;
    #pragma unroll
    for (int i = 0; i < 4; i++) {
        const int gm = m0 + wm + i * 16 + quad * 4;
        #pragma unroll
        for (int j = 0; j < 4; j++) {
            const int gn = n0 + wn + j * 16 + col;
            #pragma unroll
            for (int r = 0; r < 4; r++)
                O[(size_t)(gm + r) * NN + gn] = f2bf(acc[i][j][r]);
        }
    }
}

// ---------------- norms from qT/kT: qn2[b][n] = sum_o qT[n][o]^2 ----------
__device__ __forceinline__ float sq2(uint32_t w2) {
    float a = __builtin_bit_cast(float, w2 << 16);
    float b = __builtin_bit_cast(float, w2 & 0xFFFF0000u);
    return a * a + b * b;
}
__global__ __launch_bounds__(256) void norms_kernel(
    const ushort_t* __restrict__ qT, const ushort_t* __restrict__ kT,
    float* __restrict__ qn2, float* __restrict__ kn2)
{
    const int z = blockIdx.y;          // b*2 + which
    const int b = z >> 1;
    const ushort_t* src = ((z & 1) ? kT : qT) + (size_t)b * NN * CC;
    float* dst = ((z & 1) ? kn2 : qn2) + b * NN;
    const int t = threadIdx.x, lane = t & 63, w = t >> 6;
    const int row = blockIdx.x * 4 + w;
    const ushort_t* p = src + (size_t)row * CC;
    float s = 0.f;
    #pragma unroll
    for (int it = 0; it < 4; it++) {
        uint4 u = *(const uint4*)(p + (size_t)(lane + it * 64) * 8);
        s += sq2(u.x) + sq2(u.y) + sq2(u.z) + sq2(u.w);
    }
    #pragma unroll
    for (int o = 32; o; o >>= 1) s += __shfl_down(s, o, 64);
    if (lane == 0) dst[row] = s;
}

// ---------------- softmax row n over m, scaled by rsqrt(qn2*kn2), mask ----
__global__ __launch_bounds__(256) void softmax_kernel(
    ushort_t* __restrict__ S, const float* __restrict__ qn2,
    const float* __restrict__ kn2, const float* __restrict__ mask)
{
    const int n = blockIdx.x, b = blockIdx.y;
    ushort_t* row = S + ((size_t)b * NN + n) * NN;
    const float qinv = rsqrtf(qn2[b * NN + n]);
    const float mval = mask[b * NN + n];
    const int t = threadIdx.x;
    float v[9];
    float vmax = -3.4e38f;
    #pragma unroll
    for (int i = 0; i < 9; i++) {
        int idx = t + i * 256;
        float s = bf2f(row[idx]) * qinv * rsqrtf(kn2[b * NN + idx]);
        v[i] = s;
        vmax = fmaxf(vmax, s);
    }
    __shared__ float red[8];
    int lane = t & 63, wid = t >> 6;
    #pragma unroll
    for (int o = 32; o; o >>= 1) vmax = fmaxf(vmax, __shfl_down(vmax, o, 64));
    if (!lane) red[wid] = vmax;
    __syncthreads();
    vmax = fmaxf(fmaxf(red[0], red[1]), fmaxf(red[2], red[3]));
    float s = 0.f;
    #pragma unroll
    for (int i = 0; i < 9; i++) { v[i] = __expf(v[i] - vmax); s += v[i]; }
    #pragma unroll
    for (int o = 32; o; o >>= 1) s += __shfl_down(s, o, 64);
    if (!lane) red[4 + wid] = s;
    __syncthreads();
    s = red[4] + red[5] + red[6] + red[7];
    const float scale = mval / s;
    #pragma unroll
    for (int i = 0; i < 9; i++) row[t + i * 256] = f2bf(v[i] * scale);
}

// ---------------- out: new_x[c][n] = sum_m xbf[c][m]*att[n][m]; fused loss -
__global__ __launch_bounds__(256) void gemm_out_loss(
    const ushort_t* __restrict__ xbf, const ushort_t* __restrict__ att,
    const float* __restrict__ x, const float* __restrict__ gamma,
    float* __restrict__ accf)
{
    __shared__ __align__(16) ushort_t sA[128 * 32];
    __shared__ __align__(16) ushort_t sB[128 * 32];
    const int b = blockIdx.z;
    const int m0 = blockIdx.y * 128;   // c
    const int n0 = blockIdx.x * 128;   // n
    f32x4 acc[4][4];
    const f32x4 zz = {0.f, 0.f, 0.f, 0.f};
    #pragma unroll
    for (int i = 0; i < 4; i++)
        #pragma unroll
        for (int j = 0; j < 4; j++) acc[i][j] = zz;
    mfma_mainloop(xbf + (size_t)b * CC * NN, att + (size_t)b * NN * NN, NN,
                  m0, n0, sA, sB, acc);
    const int t = threadIdx.x, lane = t & 63, w = t >> 6;
    const int wm = (w >> 1) * 64, wn = (w & 1) * 64;
    const int col = lane & 15, quad = lane >> 4;
    const float g = gamma[0];
    const float* Xb = x + (size_t)b * CC * NN;
    float lsum = 0.f;
    unsigned int lcnt = 0;
    #pragma unroll
    for (int i = 0; i < 4; i++) {
        const int gm = m0 + wm + i * 16 + quad * 4;   // c
        #pragma unroll
        for (int j = 0; j < 4; j++) {
            const int gn = n0 + wn + j * 16 + col;    // n
            #pragma unroll
            for (int r = 0; r < 4; r++) {
                float xv = Xb[(size_t)(gm + r) * NN + gn];
                float d = xv - g * acc[i][j][r];
                float r2 = d * d;
                lsum += r2;
                lcnt += (r2 != 0.f) ? 1u : 0u;
            }
        }
    }
    #pragma unroll
    for (int o = 32; o; o >>= 1) {
        lsum += __shfl_down(lsum, o, 64);
        lcnt += __shfl_down(lcnt, o, 64);
    }
    __shared__ float rs[4];
    __shared__ unsigned int rc[4];
    if (!lane) { rs[w] = lsum; rc[w] = lcnt; }
    __syncthreads();
    if (t == 0) {
        double tot = (double)rs[0] + rs[1] + rs[2] + rs[3];
        unsigned int ct = rc[0] + rc[1] + rc[2] + rc[3];
        atomicAdd((double*)accf, tot);
        atomicAdd(((unsigned int*)accf) + 2, ct);
    }
}

__global__ void finalize_kernel(const float* __restrict__ accf, float* __restrict__ out) {
    double s = ((const double*)accf)[0];
    unsigned int c = ((const unsigned int*)accf)[2];
    out[0] = (float)(s / (double)c);
}

extern "C" void kernel_launch(void* const* d_in, const int* in_sizes, int n_in,
                              void* d_out, int out_size, void* d_ws, size_t ws_size,
                              hipStream_t stream) {
    const float* x     = (const float*)d_in[0];
    const float* cam   = (const float*)d_in[1];
    const float* Wq    = (const float*)d_in[2];
    const float* bq    = (const float*)d_in[3];
    const float* Wk    = (const float*)d_in[4];
    const float* bk    = (const float*)d_in[5];
    const float* gamma = (const float*)d_in[6];

    uint8_t* ws = (uint8_t*)d_ws;
    size_t off = 0;
    auto alloc = [&](size_t bytes) {
        void* p = ws + off;
        off = (off + bytes + 255) & ~(size_t)255;
        return p;
    };
    ushort_t* qT   = (ushort_t*)alloc((size_t)BB * NN * CC * 2);
    ushort_t* kT   = (ushort_t*)alloc((size_t)BB * NN * CC * 2);
    ushort_t* S    = (ushort_t*)alloc((size_t)BB * NN * NN * 2);  // scores -> att
    ushort_t* xT   = (ushort_t*)alloc((size_t)BB * NN * CC * 2);
    ushort_t* xbf  = (ushort_t*)alloc((size_t)BB * CC * NN * 2);
    ushort_t* Wqb  = (ushort_t*)alloc((size_t)CC * CC * 2);
    ushort_t* Wkb  = (ushort_t*)alloc((size_t)CC * CC * 2);
    float*    qn2  = (float*)alloc((size_t)BB * NN * 4);
    float*    kn2  = (float*)alloc((size_t)BB * NN * 4);
    float*    mbuf = (float*)alloc((size_t)BB * NN * 4);
    float*    acc  = (float*)alloc(16);

    hipLaunchKernelGGL(init_kernel, dim3(1), dim3(64), 0, stream, acc);
    hipLaunchKernelGGL(mask_kernel, dim3((BB * NN + 255) / 256), dim3(256), 0, stream,
                       cam, mbuf);
    hipLaunchKernelGGL(conv_w, dim3(2 * CC * CC / 4 / 256), dim3(256), 0, stream,
                       Wq, Wk, Wqb, Wkb);
    hipLaunchKernelGGL(conv_x, dim3(NN / 32, CC / 32, BB), dim3(32, 8), 0, stream,
                       x, xbf, xT);
    hipLaunchKernelGGL(gemm_proj, dim3(CC / 128, NN / 128, BB), dim3(256), 0, stream,
                       xT, Wqb, bq, qT);
    hipLaunchKernelGGL(gemm_proj, dim3(CC / 128, NN / 128, BB), dim3(256), 0, stream,
                       xT, Wkb, bk, kT);
    hipLaunchKernelGGL(norms_kernel, dim3(NN / 4, 2 * BB), dim3(256), 0, stream,
                       qT, kT, qn2, kn2);
    hipLaunchKernelGGL(gemm_energy, dim3(NN / 128, NN / 128, BB), dim3(256), 0, stream,
                       qT, kT, S);
    hipLaunchKernelGGL(softmax_kernel, dim3(NN, BB), dim3(256), 0, stream,
                       S, qn2, kn2, mbuf);
    hipLaunchKernelGGL(gemm_out_loss, dim3(NN / 128, CC / 128, BB), dim3(256), 0, stream,
                       xbf, S, x, gamma, acc);
    hipLaunchKernelGGL(finalize_kernel, dim3(1), dim3(1), 0, stream, acc, (float*)d_out);
}